// Round 3
// baseline (660.200 us; speedup 1.0000x reference)
//
#include <hip/hip_runtime.h>

// NormConv2d: depthwise 3x3 correlation with L2-normalized filters, divided by
// per-patch L2 norm. x: (16,3,1024,1024) fp32, w: (3,1,3,3) fp32, zero-pad 1.
//
// Round 3: same row-tiled sliding window as round 2, but with PREFETCH
// DISTANCE 1. Round-2 consumed row y+1 in the same iteration it was loaded
// (distance 0 -> vmcnt(0) stall every row; counters showed VALU 28%/HBM 33%/
// occ 48% = latency-bound). Now a 4-slot rotating buffer: iteration i issues
// the load for row y0+i+2 and computes from rows loaded >=1 iteration ago,
// so the compiler's partial vmcnt waits keep ~3 loads in flight per wave.
// __launch_bounds__(256,8): VGPR<=64 -> 8 waves/SIMD resident (was 44 VGPR,
// +1 row buffer ~= 52, no spill).

#define HH 1024
#define WW 1024
#define CC 3
#define NN 16
#define ROWS 8
#define TILES (HH / ROWS)        // 128 tiles per plane
#define NBLK (NN * CC * TILES)   // 6144 blocks

__device__ __forceinline__ void load_row(const float* __restrict__ base, int y,
                                         int x0, float* __restrict__ dst)
{
    if ((unsigned)y >= (unsigned)HH) {   // zero-pad top/bottom (block-uniform)
#pragma unroll
        for (int k = 0; k < 6; ++k) dst[k] = 0.f;
    } else {
        const float* p = base + y * WW;
        const float4 c4 = *(const float4*)(p + x0);       // 16B-aligned
        dst[0] = (x0 > 0)      ? p[x0 - 1] : 0.f;         // left halo (L1 hit)
        dst[1] = c4.x; dst[2] = c4.y; dst[3] = c4.z; dst[4] = c4.w;
        dst[5] = (x0 + 4 < WW) ? p[x0 + 4] : 0.f;         // right halo
    }
}

__global__ __launch_bounds__(256, 8) void normconv_kernel(
    const float* __restrict__ x, const float* __restrict__ w, float* __restrict__ out)
{
    // XCD-aware swizzle: blocks with equal (b & 7) — same XCD under
    // round-robin dispatch — cover a contiguous logical tile range.
    const int b     = blockIdx.x;
    const int L     = (b & 7) * (NBLK / 8) + (b >> 3);
    const int tile  = L & (TILES - 1);
    const int plane = L >> 7;            // L / TILES
    const int c     = plane % CC;

    // Normalized weights — block-uniform, scalarized by the compiler
    float wn[9];
    float s = 0.f;
#pragma unroll
    for (int i = 0; i < 9; ++i) { float wi = w[c * 9 + i]; wn[i] = wi; s += wi * wi; }
    const float winv = rsqrtf(s);
#pragma unroll
    for (int i = 0; i < 9; ++i) wn[i] *= winv;

    const int x0 = threadIdx.x << 2;                 // 4 outputs per thread
    const int y0 = tile * ROWS;
    const float* base  = x   + (size_t)plane * (HH * WW);
    float*       obase = out + (size_t)plane * (HH * WW);

    // 4-slot rotating window; slot (y - y0 + 1) & 3 holds input row y.
    float v[4][6];
    load_row(base, y0 - 1, x0, v[0]);
    load_row(base, y0,     x0, v[1]);
    load_row(base, y0 + 1, x0, v[2]);

#pragma unroll
    for (int i = 0; i < ROWS; ++i) {
        // Prefetch row y0+i+2 (consumed next iteration). Last needed input
        // row is y0+ROWS, issued at i == ROWS-2; skip the dead prefetch at
        // i == ROWS-1 (static condition — pruned at compile time).
        if (i < ROWS - 1) load_row(base, y0 + i + 2, x0, v[(i + 3) & 3]);

        const float* r0 = v[(i + 0) & 3];
        const float* r1 = v[(i + 1) & 3];
        const float* r2 = v[(i + 2) & 3];

        float4 o;
        float* op = &o.x;
#pragma unroll
        for (int j = 0; j < 4; ++j) {
            float num = 0.f, sq = 0.f;
#pragma unroll
            for (int k = 0; k < 3; ++k) {
                const float a0 = r0[j + k], a1 = r1[j + k], a2 = r2[j + k];
                num += a0 * wn[k] + a1 * wn[3 + k] + a2 * wn[6 + k];
                sq  += a0 * a0 + a1 * a1 + a2 * a2;
            }
            op[j] = num * rsqrtf(sq);
        }
        *(float4*)(obase + (size_t)(y0 + i) * WW + x0) = o;
    }
}

extern "C" void kernel_launch(void* const* d_in, const int* in_sizes, int n_in,
                              void* d_out, int out_size, void* d_ws, size_t ws_size,
                              hipStream_t stream) {
    const float* x = (const float*)d_in[0];
    const float* w = (const float*)d_in[1];
    float* out = (float*)d_out;

    normconv_kernel<<<NBLK, 256, 0, stream>>>(x, w, out);
}